// Round 2
// baseline (143.844 us; speedup 1.0000x reference)
//
#include <hip/hip_runtime.h>
#include <hip/hip_bf16.h>

#define D_NODE 80
#define EDGE_ITERS 8   // 16-edge tiles per wave per launch

typedef __attribute__((ext_vector_type(8))) short short8;
typedef __attribute__((ext_vector_type(4))) float f32x4;

__device__ __forceinline__ float bf16lo(unsigned u) {
    return __uint_as_float(u << 16);
}
__device__ __forceinline__ float bf16hi(unsigned u) {
    return __uint_as_float(u & 0xffff0000u);
}
__device__ __forceinline__ unsigned packbf2(float a, float b) {
    __hip_bfloat162 h = __float22bfloat162_rn(make_float2(a, b));
    union { __hip_bfloat162 h2; unsigned u; } cv; cv.h2 = h;
    return cv.u;   // low 16 bits = a, high = b
}
__device__ __forceinline__ short f2bf(float f) {
    __hip_bfloat16 h = __float2bfloat16(f);
    union { __hip_bfloat16 h1; short s; } cv; cv.h1 = h;
    return cv.s;
}

// Kernel 1: per-node projection, bf16 outputs.
// PS[n][j] = x[n] @ W1[0:80][j]
// PD[n][j] = x[n] @ W1[81:161][j] + b1[j] + W1[80][j]   (const edge feat folded)
__global__ __launch_bounds__(256, 4) void proj_kernel(
    const float* __restrict__ X, const float* __restrict__ W1,
    const float* __restrict__ b1,
    unsigned short* __restrict__ PS, unsigned short* __restrict__ PD, int N)
{
    __shared__ float sW[161 * 32];
    for (int i = threadIdx.x; i < 161 * 32; i += 256) sW[i] = W1[i];
    __syncthreads();

    int n = blockIdx.x * 256 + threadIdx.x;
    if (n >= N) return;

    float accS[32], accD[32];
#pragma unroll
    for (int j = 0; j < 32; ++j) {
        accS[j] = 0.0f;
        accD[j] = b1[j] + sW[80 * 32 + j];
    }

    const float4* x4 = (const float4*)(X + (size_t)n * D_NODE);
#pragma unroll
    for (int k4 = 0; k4 < D_NODE / 4; ++k4) {
        float4 xv = x4[k4];
        float xs[4] = {xv.x, xv.y, xv.z, xv.w};
#pragma unroll
        for (int kk = 0; kk < 4; ++kk) {
            int k = k4 * 4 + kk;
            float xk = xs[kk];
#pragma unroll
            for (int j4 = 0; j4 < 8; ++j4) {
                float4 ws = *(const float4*)&sW[k * 32 + j4 * 4];
                float4 wd = *(const float4*)&sW[(81 + k) * 32 + j4 * 4];
                accS[4 * j4 + 0] += xk * ws.x;
                accS[4 * j4 + 1] += xk * ws.y;
                accS[4 * j4 + 2] += xk * ws.z;
                accS[4 * j4 + 3] += xk * ws.w;
                accD[4 * j4 + 0] += xk * wd.x;
                accD[4 * j4 + 1] += xk * wd.y;
                accD[4 * j4 + 2] += xk * wd.z;
                accD[4 * j4 + 3] += xk * wd.w;
            }
        }
    }

    unsigned uS[16], uD[16];
#pragma unroll
    for (int j = 0; j < 16; ++j) {
        uS[j] = packbf2(accS[2 * j], accS[2 * j + 1]);
        uD[j] = packbf2(accD[2 * j], accD[2 * j + 1]);
    }
    uint4* os = (uint4*)(PS + (size_t)n * 32);
    uint4* od = (uint4*)(PD + (size_t)n * 32);
#pragma unroll
    for (int q = 0; q < 4; ++q) {
        os[q] = make_uint4(uS[4*q], uS[4*q+1], uS[4*q+2], uS[4*q+3]);
        od[q] = make_uint4(uD[4*q], uD[4*q+1], uD[4*q+2], uD[4*q+3]);
    }
}

// Kernel 2: per-edge tail via MFMA.
// Per wave-iteration: 16 edges. A-frag = relu(PS[s] + PD[d]) in bf16
// (lane: edge = lane&15, k-slots = (lane>>4)*8 + 0..7).
// Layer2: 2x mfma_f32_16x16x32_bf16 with W2 held in B-frags, C init = b2.
// Layer3 + log_softmax: per-lane partials + shfl_xor butterfly over feature dim.
__global__ __launch_bounds__(256, 4) void edge_kernel(
    const int* __restrict__ ei,
    const unsigned short* __restrict__ PS, const unsigned short* __restrict__ PD,
    const float* __restrict__ W2, const float* __restrict__ b2,
    const float* __restrict__ W3, const float* __restrict__ b3,
    float* __restrict__ out, int E)
{
    const int tid  = threadIdx.x;
    const int wave = tid >> 6;
    const int lane = tid & 63;
    const int lg   = lane & 15;   // edge-in-tile (A rows) / feature col (B,C)
    const int g    = lane >> 4;   // k-group

    // B fragments: slot j <-> k = g*8 + j (same bijection used for A packing)
    short8 B0, B1;
#pragma unroll
    for (int j = 0; j < 8; ++j) {
        int k = g * 8 + j;
        B0[j] = f2bf(W2[k * 32 + lg]);
        B1[j] = f2bf(W2[k * 32 + 16 + lg]);
    }
    const float bias0 = b2[lg];
    const float bias1 = b2[16 + lg];
    const float w00 = W3[lg * 2 + 0],        w01 = W3[lg * 2 + 1];
    const float w10 = W3[(16 + lg) * 2 + 0], w11 = W3[(16 + lg) * 2 + 1];
    const float b30 = b3[0], b31 = b3[1];

    long base = ((long)blockIdx.x * 4 + wave) * (16 * EDGE_ITERS);

#pragma unroll 2
    for (int it = 0; it < EDGE_ITERS; ++it) {
        long ebase = base + (long)it * 16;
        if (ebase >= E) break;

        long e = ebase + lg;
        int ec = (e < E) ? (int)e : 0;
        int s = ei[ec];
        int d = ei[(size_t)E + ec];

        uint4 av = *(const uint4*)(PS + (size_t)s * 32 + g * 8);
        uint4 bv = *(const uint4*)(PD + (size_t)d * 32 + g * 8);

        union { uint4 u; short8 s8; } A;
        A.u.x = packbf2(fmaxf(bf16lo(av.x) + bf16lo(bv.x), 0.f),
                        fmaxf(bf16hi(av.x) + bf16hi(bv.x), 0.f));
        A.u.y = packbf2(fmaxf(bf16lo(av.y) + bf16lo(bv.y), 0.f),
                        fmaxf(bf16hi(av.y) + bf16hi(bv.y), 0.f));
        A.u.z = packbf2(fmaxf(bf16lo(av.z) + bf16lo(bv.z), 0.f),
                        fmaxf(bf16hi(av.z) + bf16hi(bv.z), 0.f));
        A.u.w = packbf2(fmaxf(bf16lo(av.w) + bf16lo(bv.w), 0.f),
                        fmaxf(bf16hi(av.w) + bf16hi(bv.w), 0.f));

        f32x4 c0 = {bias0, bias0, bias0, bias0};
        f32x4 c1 = {bias1, bias1, bias1, bias1};
        c0 = __builtin_amdgcn_mfma_f32_16x16x32_bf16(A.s8, B0, c0, 0, 0, 0);
        c1 = __builtin_amdgcn_mfma_f32_16x16x32_bf16(A.s8, B1, c1, 0, 0, 0);

        // h2 = relu(c); layer-3 partials over this lane's 2 features
        float p0[4], p1[4];
#pragma unroll
        for (int r = 0; r < 4; ++r) {
            float ha = fmaxf(c0[r], 0.f);
            float hb = fmaxf(c1[r], 0.f);
            p0[r] = ha * w00 + hb * w10;
            p1[r] = ha * w01 + hb * w11;
        }
        // reduce across the 16-lane feature dimension
#pragma unroll
        for (int m = 1; m < 16; m <<= 1) {
#pragma unroll
            for (int r = 0; r < 4; ++r) {
                p0[r] += __shfl_xor(p0[r], m, 64);
                p1[r] += __shfl_xor(p1[r], m, 64);
            }
        }
        // lanes 0..7 of each 16-group store: r = lg>>1 edge-row, c = lg&1 class
        if (lg < 8) {
            int r = lg >> 1, c = lg & 1;
            long eo = ebase + g * 4 + r;
            if (eo < E) {
                float l0 = p0[r] + b30;
                float l1 = p1[r] + b31;
                float mm = fmaxf(l0, l1);
                float z  = __expf(l0 - mm) + __expf(l1 - mm);
                float lse = mm + __logf(z);
                out[2 * eo + c] = (c ? l1 : l0) - lse;
            }
        }
    }
}

extern "C" void kernel_launch(void* const* d_in, const int* in_sizes, int n_in,
                              void* d_out, int out_size, void* d_ws, size_t ws_size,
                              hipStream_t stream) {
    const float* X  = (const float*)d_in[0];
    const int*   ei = (const int*)d_in[1];
    const float* W1 = (const float*)d_in[2];
    const float* b1 = (const float*)d_in[3];
    const float* W2 = (const float*)d_in[4];
    const float* b2 = (const float*)d_in[5];
    const float* W3 = (const float*)d_in[6];
    const float* b3 = (const float*)d_in[7];
    float* out = (float*)d_out;

    int N = in_sizes[0] / D_NODE;   // 100000
    int E = in_sizes[1] / 2;        // 1600000

    unsigned short* PS = (unsigned short*)d_ws;            // N*32 bf16 = 6.4 MB
    unsigned short* PD = PS + (size_t)N * 32;              // N*32 bf16 = 6.4 MB

    proj_kernel<<<(N + 255) / 256, 256, 0, stream>>>(X, W1, b1, PS, PD, N);

    int edges_per_block = 4 * 16 * EDGE_ITERS;             // 512
    int nblk = (E + edges_per_block - 1) / edges_per_block;
    edge_kernel<<<nblk, 256, 0, stream>>>(ei, PS, PD, W2, b2, W3, b3, out, E);
}

// Round 3
// 87.217 us; speedup vs baseline: 1.6493x; 1.6493x over previous
//
#include <hip/hip_runtime.h>
#include <hip/hip_bf16.h>

#define D_NODE 80
#define EDGE_ITERS 8   // 16-edge tiles per wave per launch

typedef __attribute__((ext_vector_type(8))) short short8;
typedef __attribute__((ext_vector_type(4))) float f32x4;

__device__ __forceinline__ float bf16lo(unsigned u) {
    return __uint_as_float(u << 16);
}
__device__ __forceinline__ float bf16hi(unsigned u) {
    return __uint_as_float(u & 0xffff0000u);
}
__device__ __forceinline__ unsigned packbf2(float a, float b) {
    __hip_bfloat162 h = __float22bfloat162_rn(make_float2(a, b));
    union { __hip_bfloat162 h2; unsigned u; } cv; cv.h2 = h;
    return cv.u;   // low 16 bits = a, high = b
}
__device__ __forceinline__ short f2bf(float f) {
    __hip_bfloat16 h = __float2bfloat16(f);
    union { __hip_bfloat16 h1; short s; } cv; cv.h1 = h;
    return cv.s;
}

// Kernel 1: per-node projection, bf16 outputs. 2 threads per node:
// even thread: PS[n][j] = x[n] @ W1[0:80][j]
// odd  thread: PD[n][j] = x[n] @ W1[81:161][j] + b1[j] + W1[80][j]
// Stores staged via LDS -> coalesced uint4 writes.
__global__ __launch_bounds__(256) void proj_kernel(
    const float* __restrict__ X, const float* __restrict__ W1,
    const float* __restrict__ b1,
    unsigned short* __restrict__ PS, unsigned short* __restrict__ PD, int N)
{
    __shared__ float sW[161 * 32];
    __shared__ unsigned sStage[256 * 20];   // 20-word stride: 16B-aligned + bank spread

    for (int i = threadIdx.x; i < 161 * 32 / 4; i += 256)
        ((float4*)sW)[i] = ((const float4*)W1)[i];
    __syncthreads();

    const int t    = threadIdx.x;
    const int base = blockIdx.x * 128;
    const int node = base + (t >> 1);
    const int half = t & 1;
    const int nc   = (node < N) ? node : 0;

    float acc[32];
#pragma unroll
    for (int j = 0; j < 32; ++j)
        acc[j] = half ? (b1[j] + sW[80 * 32 + j]) : 0.0f;

    const int wbase = half ? 81 * 32 : 0;
    const float4* x4 = (const float4*)(X + (size_t)nc * D_NODE);
#pragma unroll
    for (int k4 = 0; k4 < D_NODE / 4; ++k4) {
        float4 xv = x4[k4];
        float xs[4] = {xv.x, xv.y, xv.z, xv.w};
#pragma unroll
        for (int kk = 0; kk < 4; ++kk) {
            float xk = xs[kk];
            const float4* wr = (const float4*)&sW[wbase + (k4 * 4 + kk) * 32];
#pragma unroll
            for (int j4 = 0; j4 < 8; ++j4) {
                float4 w = wr[j4];
                acc[4 * j4 + 0] += xk * w.x;
                acc[4 * j4 + 1] += xk * w.y;
                acc[4 * j4 + 2] += xk * w.z;
                acc[4 * j4 + 3] += xk * w.w;
            }
        }
    }

    unsigned* st = &sStage[t * 20];
#pragma unroll
    for (int q = 0; q < 4; ++q) {
        uint4 v = make_uint4(packbf2(acc[8*q+0], acc[8*q+1]),
                             packbf2(acc[8*q+2], acc[8*q+3]),
                             packbf2(acc[8*q+4], acc[8*q+5]),
                             packbf2(acc[8*q+6], acc[8*q+7]));
        *(uint4*)&st[q * 4] = v;
    }
    __syncthreads();

    // cooperative coalesced copy: 128 rows x 16 u32-words per table
    const int limW4 = ((N - base < 128 ? N - base : 128) * 16) / 4; // uint4 count
    uint4* psw = (uint4*)(PS + (size_t)base * 32);
    uint4* pdw = (uint4*)(PD + (size_t)base * 32);
#pragma unroll
    for (int w4 = t; w4 < 512; w4 += 256) {
        if (w4 < limW4) {
            int nd = w4 >> 2, j = (w4 & 3) * 4;
            psw[w4] = *(uint4*)&sStage[(nd * 2 + 0) * 20 + j];
            pdw[w4] = *(uint4*)&sStage[(nd * 2 + 1) * 20 + j];
        }
    }
}

// Kernel 2: per-edge tail via MFMA, swapped operands.
// A = W2 halves (features on M), B = h1 edge fragment (edges on N).
// C/D: lane(g,lg) holds D[feat g*4+r][edge lg] -> layer-3 partial per lane,
// 2-round shfl_xor reduce over g, g==0 lanes store contiguous float2.
__global__ __launch_bounds__(256) void edge_kernel(
    const int* __restrict__ ei,
    const unsigned short* __restrict__ PS, const unsigned short* __restrict__ PD,
    const float* __restrict__ W2, const float* __restrict__ b2,
    const float* __restrict__ W3, const float* __restrict__ b3,
    float* __restrict__ out, int E)
{
    const int tid  = threadIdx.x;
    const int wave = tid >> 6;
    const int lane = tid & 63;
    const int lg   = lane & 15;   // edge-in-tile (B/C col)
    const int g    = lane >> 4;   // k-group / C row-group

    // A fragments: slot j <-> k = g*8 + j; A[m=lg][k] = W2[k][m]
    short8 Wa, Wb;
#pragma unroll
    for (int j = 0; j < 8; ++j) {
        int k = g * 8 + j;
        Wa[j] = f2bf(W2[k * 32 + lg]);
        Wb[j] = f2bf(W2[k * 32 + 16 + lg]);
    }
    float b2a[4], b2b[4];
    float w3a0[4], w3a1[4], w3b0[4], w3b1[4];
#pragma unroll
    for (int r = 0; r < 4; ++r) {
        int f = g * 4 + r;
        b2a[r]  = b2[f];
        b2b[r]  = b2[16 + f];
        w3a0[r] = W3[f * 2 + 0];
        w3a1[r] = W3[f * 2 + 1];
        w3b0[r] = W3[(16 + f) * 2 + 0];
        w3b1[r] = W3[(16 + f) * 2 + 1];
    }
    const float b30 = b3[0], b31 = b3[1];

    const long base = ((long)blockIdx.x * 4 + wave) * (16 * EDGE_ITERS);

    // hoist all index loads (all in flight immediately)
    int sIdx[EDGE_ITERS], dIdx[EDGE_ITERS];
#pragma unroll
    for (int it = 0; it < EDGE_ITERS; ++it) {
        long e = base + (long)it * 16 + lg;
        int ec = (e < E) ? (int)e : 0;
        sIdx[it] = ei[ec];
        dIdx[it] = ei[(size_t)E + ec];
    }

    uint4 av = *(const uint4*)(PS + (size_t)sIdx[0] * 32 + g * 8);
    uint4 bv = *(const uint4*)(PD + (size_t)dIdx[0] * 32 + g * 8);

#pragma unroll
    for (int it = 0; it < EDGE_ITERS; ++it) {
        uint4 avn, bvn;
        if (it + 1 < EDGE_ITERS) {   // prefetch next tile's rows
            avn = *(const uint4*)(PS + (size_t)sIdx[it + 1] * 32 + g * 8);
            bvn = *(const uint4*)(PD + (size_t)dIdx[it + 1] * 32 + g * 8);
        }

        union { uint4 u; short8 s8; } A;
        A.u.x = packbf2(fmaxf(bf16lo(av.x) + bf16lo(bv.x), 0.f),
                        fmaxf(bf16hi(av.x) + bf16hi(bv.x), 0.f));
        A.u.y = packbf2(fmaxf(bf16lo(av.y) + bf16lo(bv.y), 0.f),
                        fmaxf(bf16hi(av.y) + bf16hi(bv.y), 0.f));
        A.u.z = packbf2(fmaxf(bf16lo(av.z) + bf16lo(bv.z), 0.f),
                        fmaxf(bf16hi(av.z) + bf16hi(bv.z), 0.f));
        A.u.w = packbf2(fmaxf(bf16lo(av.w) + bf16lo(bv.w), 0.f),
                        fmaxf(bf16hi(av.w) + bf16hi(bv.w), 0.f));

        f32x4 c0 = {b2a[0], b2a[1], b2a[2], b2a[3]};
        f32x4 c1 = {b2b[0], b2b[1], b2b[2], b2b[3]};
        c0 = __builtin_amdgcn_mfma_f32_16x16x32_bf16(Wa, A.s8, c0, 0, 0, 0);
        c1 = __builtin_amdgcn_mfma_f32_16x16x32_bf16(Wb, A.s8, c1, 0, 0, 0);

        float p0 = 0.f, p1 = 0.f;
#pragma unroll
        for (int r = 0; r < 4; ++r) {
            float ha = fmaxf(c0[r], 0.f);
            float hb = fmaxf(c1[r], 0.f);
            p0 += ha * w3a0[r] + hb * w3b0[r];
            p1 += ha * w3a1[r] + hb * w3b1[r];
        }
        p0 += __shfl_xor(p0, 16, 64);
        p0 += __shfl_xor(p0, 32, 64);
        p1 += __shfl_xor(p1, 16, 64);
        p1 += __shfl_xor(p1, 32, 64);

        if (g == 0) {
            long eo = base + (long)it * 16 + lg;
            if (eo < E) {
                float l0 = p0 + b30;
                float l1 = p1 + b31;
                float mm = fmaxf(l0, l1);
                float z  = __expf(l0 - mm) + __expf(l1 - mm);
                float lse = mm + __logf(z);
                float2 o = make_float2(l0 - lse, l1 - lse);
                *(float2*)(out + 2 * eo) = o;
            }
        }
        av = avn; bv = bvn;
    }
}

extern "C" void kernel_launch(void* const* d_in, const int* in_sizes, int n_in,
                              void* d_out, int out_size, void* d_ws, size_t ws_size,
                              hipStream_t stream) {
    const float* X  = (const float*)d_in[0];
    const int*   ei = (const int*)d_in[1];
    const float* W1 = (const float*)d_in[2];
    const float* b1 = (const float*)d_in[3];
    const float* W2 = (const float*)d_in[4];
    const float* b2 = (const float*)d_in[5];
    const float* W3 = (const float*)d_in[6];
    const float* b3 = (const float*)d_in[7];
    float* out = (float*)d_out;

    int N = in_sizes[0] / D_NODE;   // 100000
    int E = in_sizes[1] / 2;        // 1600000

    unsigned short* PS = (unsigned short*)d_ws;            // N*32 bf16 = 6.4 MB
    unsigned short* PD = PS + (size_t)N * 32;              // N*32 bf16 = 6.4 MB

    proj_kernel<<<(N + 127) / 128, 256, 0, stream>>>(X, W1, b1, PS, PD, N);

    int edges_per_block = 4 * 16 * EDGE_ITERS;             // 512
    int nblk = (E + edges_per_block - 1) / edges_per_block;
    edge_kernel<<<nblk, 256, 0, stream>>>(ei, PS, PD, W2, b2, W3, b3, out, E);
}